// Round 1
// baseline (295.275 us; speedup 1.0000x reference)
//
#include <hip/hip_runtime.h>

// Problem constants (match reference)
#define Tcnt 32768      // B*S
#define Gn   2
#define Vn   320
#define Dn   128        // CVD / G
#define DIMK 512
#define GV   640        // G*V

constexpr int BM = 128, BN = 128, BK = 16;

// ---------------- GEMM: logits = hs @ W + b, written into dist region ----------------
__global__ __launch_bounds__(256) void gemm_logits_kernel(
    const float* __restrict__ A,     // [T, DIMK]
    const float* __restrict__ W,     // [DIMK, GV]
    const float* __restrict__ bias,  // [GV]
    float* __restrict__ C)           // [T, GV] (dist region, used as logits scratch)
{
    __shared__ float As[BK][BM + 4]; // stored transposed: As[k][m]
    __shared__ float Bs[BK][BN + 4];

    const int tid = threadIdx.x;
    const int bx = blockIdx.x % (GV / BN);  // 5 N-tiles
    const int by = blockIdx.x / (GV / BN);  // 256 M-tiles

    const int tx = tid & 15, ty = tid >> 4;
    const int trow = ty * 8, tcol = tx * 8;

    float acc[8][8] = {};

    // global load assignments (2 float4 for A, 2 for B per thread per K-tile)
    const int arow = tid >> 2;            // 0..63
    const int acol = (tid & 3) << 2;      // 0,4,8,12
    const int brow = tid >> 5;            // 0..7
    const int bcol = (tid & 31) << 2;     // 0..124

    const float* Abase = A + (size_t)(by * BM) * DIMK;

    for (int k0 = 0; k0 < DIMK; k0 += BK) {
        float4 a0 = *(const float4*)(Abase + (size_t)arow * DIMK + k0 + acol);
        float4 a1 = *(const float4*)(Abase + (size_t)(arow + 64) * DIMK + k0 + acol);
        float4 b0 = *(const float4*)(W + (size_t)(k0 + brow) * GV + bx * BN + bcol);
        float4 b1 = *(const float4*)(W + (size_t)(k0 + brow + 8) * GV + bx * BN + bcol);

        __syncthreads();   // previous iteration's compute done reading LDS

        As[acol + 0][arow] = a0.x;
        As[acol + 1][arow] = a0.y;
        As[acol + 2][arow] = a0.z;
        As[acol + 3][arow] = a0.w;
        As[acol + 0][arow + 64] = a1.x;
        As[acol + 1][arow + 64] = a1.y;
        As[acol + 2][arow + 64] = a1.z;
        As[acol + 3][arow + 64] = a1.w;
        *(float4*)&Bs[brow][bcol]     = b0;
        *(float4*)&Bs[brow + 8][bcol] = b1;

        __syncthreads();

        #pragma unroll
        for (int kk = 0; kk < BK; ++kk) {
            float4 aq0 = *(const float4*)&As[kk][trow];
            float4 aq1 = *(const float4*)&As[kk][trow + 4];
            float4 bq0 = *(const float4*)&Bs[kk][tcol];
            float4 bq1 = *(const float4*)&Bs[kk][tcol + 4];
            float av[8] = {aq0.x, aq0.y, aq0.z, aq0.w, aq1.x, aq1.y, aq1.z, aq1.w};
            float bv[8] = {bq0.x, bq0.y, bq0.z, bq0.w, bq1.x, bq1.y, bq1.z, bq1.w};
            #pragma unroll
            for (int i = 0; i < 8; ++i)
                #pragma unroll
                for (int j = 0; j < 8; ++j)
                    acc[i][j] = fmaf(av[i], bv[j], acc[i][j]);
        }
    }

    const int gcol = bx * BN + tcol;
    float4 bias0 = *(const float4*)(bias + gcol);
    float4 bias1 = *(const float4*)(bias + gcol + 4);
    #pragma unroll
    for (int i = 0; i < 8; ++i) {
        size_t row = (size_t)(by * BM + trow + i);
        float4 o0, o1;
        o0.x = acc[i][0] + bias0.x; o0.y = acc[i][1] + bias0.y;
        o0.z = acc[i][2] + bias0.z; o0.w = acc[i][3] + bias0.w;
        o1.x = acc[i][4] + bias1.x; o1.y = acc[i][5] + bias1.y;
        o1.z = acc[i][6] + bias1.z; o1.w = acc[i][7] + bias1.w;
        *(float4*)(C + row * GV + gcol)     = o0;
        *(float4*)(C + row * GV + gcol + 4) = o1;
    }
}

// ---------------- epilogue: argmax(logits+gumbel) gather + softmax(logits) in place ----
__global__ __launch_bounds__(256) void vq_epilogue_kernel(
    const float* __restrict__ gumbels, // [T*G, V]
    const float* __restrict__ cv,      // [G*V, D]
    float* __restrict__ dist,          // [T*G, V]  (holds logits on entry)
    float* __restrict__ out)           // [T, G*D]
{
    const int lane = threadIdx.x & 63;
    const int wid  = threadIdx.x >> 6;
    const int r = blockIdx.x * 4 + wid;           // row in [0, T*G)

    const float* lrow = dist    + (size_t)r * Vn;
    const float* grow = gumbels + (size_t)r * Vn;

    float lv[5];
    float best = -1e30f; int bidx = 0;
    float lmax = -1e30f;
    #pragma unroll
    for (int j = 0; j < 5; ++j) {
        int v = lane + j * 64;
        lv[j] = lrow[v];
        float s = lv[j] + grow[v];
        if (s > best) { best = s; bidx = v; }
        lmax = fmaxf(lmax, lv[j]);
    }

    #pragma unroll
    for (int off = 32; off > 0; off >>= 1) {
        float ob = __shfl_xor(best, off);
        int   oi = __shfl_xor(bidx, off);
        if (ob > best || (ob == best && oi < bidx)) { best = ob; bidx = oi; }
        float om = __shfl_xor(lmax, off);
        lmax = fmaxf(lmax, om);
    }

    float ev[5]; float ssum = 0.f;
    #pragma unroll
    for (int j = 0; j < 5; ++j) { ev[j] = expf(lv[j] - lmax); ssum += ev[j]; }
    #pragma unroll
    for (int off = 32; off > 0; off >>= 1) ssum += __shfl_xor(ssum, off);
    float inv = 1.0f / ssum;

    float* drow = dist + (size_t)r * Vn;
    #pragma unroll
    for (int j = 0; j < 5; ++j) drow[lane + j * 64] = ev[j] * inv;

    // gather selected codevector
    const int g = r & 1;
    const size_t t = (size_t)(r >> 1);
    const float* cvrow = cv + ((size_t)(g * Vn + bidx)) * Dn;
    float* orow = out + t * (size_t)(Gn * Dn) + (size_t)g * Dn;
    orow[lane]      = cvrow[lane];
    orow[lane + 64] = cvrow[lane + 64];
}

extern "C" void kernel_launch(void* const* d_in, const int* in_sizes, int n_in,
                              void* d_out, int out_size, void* d_ws, size_t ws_size,
                              hipStream_t stream) {
    const float* hs  = (const float*)d_in[0];  // [8,4096,512]
    const float* W   = (const float*)d_in[1];  // [512,640]
    const float* b   = (const float*)d_in[2];  // [640]
    const float* cv  = (const float*)d_in[3];  // [640,128]
    const float* gum = (const float*)d_in[4];  // [65536,320]

    float* out  = (float*)d_out;                         // [32768, 256]
    float* dist = out + (size_t)Tcnt * (Gn * Dn);        // [32768, 640] == [T*G, V]

    // logits into dist region
    dim3 g1((Tcnt / BM) * (GV / BN));   // 256 * 5 = 1280 blocks
    gemm_logits_kernel<<<g1, 256, 0, stream>>>(hs, W, b, dist);

    // fused argmax-gather + softmax (in-place on dist)
    dim3 g2((Tcnt * Gn) / 4);           // 16384 blocks, 4 rows/block
    vq_epilogue_kernel<<<g2, 256, 0, stream>>>(gum, cv, dist, out);
}

// Round 2
// 131.460 us; speedup vs baseline: 2.2461x; 2.2461x over previous
//
#include <hip/hip_runtime.h>

#define Tcnt 32768      // B*S
#define Gn   2
#define Vn   320
#define Dn   128
#define DIMK 512
#define GV   640        // G*V

typedef __attribute__((ext_vector_type(8))) short bf16x8;
typedef __attribute__((ext_vector_type(4))) float f32x4;

constexpr int BM = 128, BN = 128, BK = 32;
constexpr int KP = BK + 8;     // padded row extent in ushorts (80 B rows, 16B-aligned)

__device__ inline ushort f2bf(float x) {
    unsigned u = __float_as_uint(x);
    unsigned r = (u + 0x7fffu + ((u >> 16) & 1u)) >> 16;   // RNE
    return (ushort)r;
}

// ---------------- GEMM: logits = hs @ W + b  (bf16 MFMA, fp32 accumulate) -------------
__global__ __launch_bounds__(256) void gemm_bf16_kernel(
    const float* __restrict__ A,     // [T, DIMK] fp32
    const float* __restrict__ W,     // [DIMK, GV] fp32
    const float* __restrict__ bias,  // [GV]
    float* __restrict__ C)           // [T, GV]  (dist region used as logits scratch)
{
    __shared__ ushort As[BM * KP];
    __shared__ ushort Bs[BN * KP];   // stored transposed: Bs[n][k]

    const int tid = threadIdx.x;
    const int bx = blockIdx.x % (GV / BN);   // 5 N-tiles (inner -> A-tile L2/L3 reuse)
    const int by = blockIdx.x / (GV / BN);   // 256 M-tiles
    const int lane = tid & 63, wid = tid >> 6;
    const int wm = (wid >> 1) * 64, wn = (wid & 1) * 64;
    const int lr = lane & 15, lk = lane >> 4;

    const int sr = tid >> 3;   // 0..31
    const int sc = tid & 7;    // 0..7

    f32x4 acc[4][4] = {};

    for (int k0 = 0; k0 < DIMK; k0 += BK) {
        // --- global loads (fp32) ---
        float4 av[4], bv[4];
        #pragma unroll
        for (int q = 0; q < 4; ++q) {
            int m = sr + 32 * q;
            av[q] = *(const float4*)(A + (size_t)(by * BM + m) * DIMK + k0 + sc * 4);
        }
        #pragma unroll
        for (int q = 0; q < 4; ++q) {
            int c = sc * 4 + q * 32;
            bv[q] = *(const float4*)(W + (size_t)(k0 + sr) * GV + bx * BN + c);
        }

        __syncthreads();   // previous compute done reading LDS

        // --- convert + stage ---
        #pragma unroll
        for (int q = 0; q < 4; ++q) {
            int m = sr + 32 * q;
            ushort* p = &As[m * KP + sc * 4];
            p[0] = f2bf(av[q].x); p[1] = f2bf(av[q].y);
            p[2] = f2bf(av[q].z); p[3] = f2bf(av[q].w);
        }
        #pragma unroll
        for (int q = 0; q < 4; ++q) {
            int c = sc * 4 + q * 32;
            Bs[(c + 0) * KP + sr] = f2bf(bv[q].x);
            Bs[(c + 1) * KP + sr] = f2bf(bv[q].y);
            Bs[(c + 2) * KP + sr] = f2bf(bv[q].z);
            Bs[(c + 3) * KP + sr] = f2bf(bv[q].w);
        }

        __syncthreads();

        // --- fragments + MFMA (A and B use the SAME k->slot mapping: permutation-safe) ---
        bf16x8 af[4], bfr[4];
        #pragma unroll
        for (int i = 0; i < 4; ++i)
            af[i] = *(const bf16x8*)&As[(wm + i * 16 + lr) * KP + lk * 8];
        #pragma unroll
        for (int i = 0; i < 4; ++i)
            bfr[i] = *(const bf16x8*)&Bs[(wn + i * 16 + lr) * KP + lk * 8];
        #pragma unroll
        for (int i = 0; i < 4; ++i)
            #pragma unroll
            for (int j = 0; j < 4; ++j)
                acc[i][j] = __builtin_amdgcn_mfma_f32_16x16x32_bf16(af[i], bfr[j], acc[i][j], 0, 0, 0);
    }

    // --- epilogue: add bias, store fp32 logits ---
    #pragma unroll
    for (int j = 0; j < 4; ++j) {
        int col = bx * BN + wn + j * 16 + lr;
        float bb = bias[col];
        #pragma unroll
        for (int i = 0; i < 4; ++i) {
            #pragma unroll
            for (int q = 0; q < 4; ++q) {
                int row = by * BM + wm + i * 16 + lk * 4 + q;   // m89-verified C/D layout
                C[(size_t)row * GV + col] = acc[i][j][q] + bb;
            }
        }
    }
}

// ------- epilogue: argmax(+exact fixup) gather + softmax(logits) in place -------------
__global__ __launch_bounds__(256) void vq_epilogue_kernel(
    const float* __restrict__ hs,      // [T, DIMK]
    const float* __restrict__ W,       // [DIMK, GV]
    const float* __restrict__ bias,    // [GV]
    const float* __restrict__ gumbels, // [T*G, V]
    const float* __restrict__ cv,      // [G*V, D]
    float* __restrict__ dist,          // [T*G, V]  (holds approx logits on entry)
    float* __restrict__ out)           // [T, G*D]
{
    const int lane = threadIdx.x & 63;
    const int wid  = threadIdx.x >> 6;
    const int r = blockIdx.x * 4 + wid;          // row in [0, T*G)

    const float* lrow = dist    + (size_t)r * Vn;
    const float* grow = gumbels + (size_t)r * Vn;

    float lv[5], s[5];
    float best = -1e30f; int bidx = 0;
    float lmax = -1e30f;
    #pragma unroll
    for (int j = 0; j < 5; ++j) {
        int v = lane + j * 64;
        lv[j] = lrow[v];
        s[j] = lv[j] + grow[v];
        if (s[j] > best) { best = s[j]; bidx = v; }
        lmax = fmaxf(lmax, lv[j]);
    }

    #pragma unroll
    for (int off = 32; off > 0; off >>= 1) {
        float ob = __shfl_xor(best, off);
        int   oi = __shfl_xor(bidx, off);
        if (ob > best || (ob == best && oi < bidx)) { best = ob; bidx = oi; }
        lmax = fmaxf(lmax, __shfl_xor(lmax, off));
    }

    // ---- argmax fixup: exact fp32 recompute of all near-tie candidates ----
    const float MARGIN = 0.0625f;
    float thr = best - MARGIN;
    unsigned long long bal[5];
    int tot = 0;
    #pragma unroll
    for (int j = 0; j < 5; ++j) {
        bal[j] = __ballot(s[j] >= thr);
        tot += __popcll(bal[j]);
    }
    const int g = r & 1;
    const size_t t = (size_t)(r >> 1);
    if (tot > 1) {
        const float* hrow = hs + t * DIMK;
        float h[8];
        #pragma unroll
        for (int i = 0; i < 8; ++i) h[i] = hrow[lane * 8 + i];
        float ebest = -1e30f; int ebidx = 0x7fffffff;
        #pragma unroll
        for (int j = 0; j < 5; ++j) {
            unsigned long long m = bal[j];
            while (m) {
                int ln = __ffsll((long long)m) - 1; m &= m - 1;
                int v = ln + j * 64;
                int gvc = g * Vn + v;
                const float* wc = W + gvc;
                float p = 0.f;
                #pragma unroll
                for (int i = 0; i < 8; ++i)
                    p = fmaf(h[i], wc[(size_t)(lane * 8 + i) * GV], p);
                #pragma unroll
                for (int off = 32; off > 0; off >>= 1) p += __shfl_xor(p, off);
                float sc2 = p + bias[gvc] + grow[v];
                if (sc2 > ebest || (sc2 == ebest && v < ebidx)) { ebest = sc2; ebidx = v; }
            }
        }
        bidx = ebidx;
    }

    // ---- softmax(logits) in place ----
    float ev[5]; float ssum = 0.f;
    #pragma unroll
    for (int j = 0; j < 5; ++j) { ev[j] = expf(lv[j] - lmax); ssum += ev[j]; }
    #pragma unroll
    for (int off = 32; off > 0; off >>= 1) ssum += __shfl_xor(ssum, off);
    float inv = 1.0f / ssum;

    float* drow = dist + (size_t)r * Vn;
    #pragma unroll
    for (int j = 0; j < 5; ++j) drow[lane + j * 64] = ev[j] * inv;

    // ---- gather selected codevector (bit-exact copy) ----
    const float* cvrow = cv + ((size_t)(g * Vn + bidx)) * Dn;
    float* orow = out + t * (size_t)(Gn * Dn) + (size_t)g * Dn;
    orow[lane]      = cvrow[lane];
    orow[lane + 64] = cvrow[lane + 64];
}

extern "C" void kernel_launch(void* const* d_in, const int* in_sizes, int n_in,
                              void* d_out, int out_size, void* d_ws, size_t ws_size,
                              hipStream_t stream) {
    const float* hs  = (const float*)d_in[0];  // [8,4096,512]
    const float* W   = (const float*)d_in[1];  // [512,640]
    const float* b   = (const float*)d_in[2];  // [640]
    const float* cv  = (const float*)d_in[3];  // [640,128]
    const float* gum = (const float*)d_in[4];  // [65536,320]

    float* out  = (float*)d_out;                      // [32768, 256]
    float* dist = out + (size_t)Tcnt * (Gn * Dn);     // [32768, 640] == [T*G, V]

    dim3 g1((Tcnt / BM) * (GV / BN));   // 1280 blocks
    gemm_bf16_kernel<<<g1, 256, 0, stream>>>(hs, W, b, dist);

    dim3 g2((Tcnt * Gn) / 4);           // 16384 blocks
    vq_epilogue_kernel<<<g2, 256, 0, stream>>>(hs, W, b, gum, cv, dist, out);
}

// Round 3
// 109.851 us; speedup vs baseline: 2.6880x; 1.1967x over previous
//
#include <hip/hip_runtime.h>

#define Tcnt 32768      // B*S
#define Gn   2
#define Vn   320
#define Dn   128
#define DIMK 512
#define GV   640        // G*V

typedef __attribute__((ext_vector_type(8))) short bf16x8;
typedef __attribute__((ext_vector_type(8))) ushort u16x8;
typedef __attribute__((ext_vector_type(4))) float f32x4;

constexpr int BM = 128, BN = 128, BK = 64;

__device__ inline ushort f2bf(float x) {
    unsigned u = __float_as_uint(x);
    unsigned r = (u + 0x7fffu + ((u >> 16) & 1u)) >> 16;   // RNE
    return (ushort)r;
}

#define AS1(p) ((const __attribute__((address_space(1))) void*)(p))
#define AS3(p) ((__attribute__((address_space(3))) void*)(p))

// ---------------- prep: hs -> bf16 (into out region), W -> bf16 transposed (ws) ------
__global__ __launch_bounds__(256) void prep_kernel(
    const float* __restrict__ hs,   // [T*DIMK]
    const float* __restrict__ W,    // [DIMK, GV]
    ushort* __restrict__ Abf,       // [T*DIMK] bf16
    ushort* __restrict__ Wt)        // [GV, DIMK] bf16 (transposed)
{
    __shared__ ushort Ls[64][72];
    const int tid = threadIdx.x;
    if (blockIdx.x < 8192) {
        // hs convert: 8 floats / thread
        size_t idx = ((size_t)blockIdx.x * 256 + tid) * 8;
        float4 a = *(const float4*)(hs + idx);
        float4 b = *(const float4*)(hs + idx + 4);
        u16x8 o;
        o[0] = f2bf(a.x); o[1] = f2bf(a.y); o[2] = f2bf(a.z); o[3] = f2bf(a.w);
        o[4] = f2bf(b.x); o[5] = f2bf(b.y); o[6] = f2bf(b.z); o[7] = f2bf(b.w);
        *(u16x8*)(Abf + idx) = o;
    } else {
        // W transpose tile 64(k) x 64(n)
        int t = blockIdx.x - 8192;              // 0..79
        int n0 = (t % 10) * 64;
        int k0 = (t / 10) * 64;
        int ln = tid & 63;
        int kq = tid >> 6;                      // 0..3
        #pragma unroll
        for (int kk = 0; kk < 16; ++kk) {
            int k = kq * 16 + kk;
            Ls[k][ln] = f2bf(W[(size_t)(k0 + k) * GV + n0 + ln]);
        }
        __syncthreads();
        #pragma unroll
        for (int nn = 0; nn < 16; ++nn) {
            int n = kq * 16 + nn;
            Wt[(size_t)(n0 + n) * DIMK + k0 + ln] = Ls[ln][n];
        }
    }
}

// ---------------- GEMM: logits = hs @ W + b  (bf16 MFMA, gll staging, swizzled) ------
__global__ __launch_bounds__(256) void gemm_bf16_kernel(
    const ushort* __restrict__ A,    // [T, DIMK] bf16
    const ushort* __restrict__ Wt,   // [GV, DIMK] bf16 (transposed)
    const float* __restrict__ bias,  // [GV]
    float* __restrict__ C)           // [T, GV] fp32 logits (dist region)
{
    __shared__ ushort As[BM * BK];   // linear [m][k], content chunk-swizzled
    __shared__ ushort Bs[BN * BK];   // linear [n][k], content chunk-swizzled

    const int tid = threadIdx.x;
    // XCD-aware bijective swizzle (nwg=1280, 1280%8==0): each XCD gets contig chunk
    const int bid = blockIdx.x;
    const int swz = (bid & 7) * 160 + (bid >> 3);
    const int bx = swz % 5;                  // N-tile (inner -> A reuse in L2)
    const int by = swz / 5;                  // M-tile

    const int lane = tid & 63, wid = tid >> 6;
    const int wm = (wid >> 1) * 64, wn = (wid & 1) * 64;
    const int lr = lane & 15, lk = lane >> 4;
    const int lrow = lane >> 3, lchunk = lane & 7;   // staging: 8 rows x 8 chunks / instr

    const ushort* Ab = A  + (size_t)(by * BM) * DIMK;
    const ushort* Bb = Wt + (size_t)(bx * BN) * DIMK;

    f32x4 acc[4][4] = {};

    for (int k0 = 0; k0 < DIMK; k0 += BK) {
        __syncthreads();   // previous compute done reading LDS
        #pragma unroll
        for (int i = 0; i < 4; ++i) {
            int q = wid * 4 + i;                 // instr id 0..15
            int row = q * 8 + lrow;              // tile row
            int sc = lchunk ^ (row & 7);         // inverse-swizzled source chunk
            __builtin_amdgcn_global_load_lds(
                AS1(Ab + (size_t)row * DIMK + k0 + sc * 8),
                AS3(&As[q * 512]), 16, 0, 0);
            __builtin_amdgcn_global_load_lds(
                AS1(Bb + (size_t)row * DIMK + k0 + sc * 8),
                AS3(&Bs[q * 512]), 16, 0, 0);
        }
        __syncthreads();   // compiler drains vmcnt(0) here

        #pragma unroll
        for (int h = 0; h < 2; ++h) {
            bf16x8 af[4], bv[4];
            #pragma unroll
            for (int i = 0; i < 4; ++i) {
                int row = wm + i * 16 + lr;
                int c = (h * 4 + lk) ^ (row & 7);    // swizzled read
                af[i] = *(const bf16x8*)&As[row * 64 + c * 8];
            }
            #pragma unroll
            for (int j = 0; j < 4; ++j) {
                int row = wn + j * 16 + lr;
                int c = (h * 4 + lk) ^ (row & 7);
                bv[j] = *(const bf16x8*)&Bs[row * 64 + c * 8];
            }
            #pragma unroll
            for (int i = 0; i < 4; ++i)
                #pragma unroll
                for (int j = 0; j < 4; ++j)
                    acc[i][j] = __builtin_amdgcn_mfma_f32_16x16x32_bf16(af[i], bv[j], acc[i][j], 0, 0, 0);
        }
    }

    #pragma unroll
    for (int j = 0; j < 4; ++j) {
        int col = bx * BN + wn + j * 16 + lr;
        float bb = bias[col];
        #pragma unroll
        for (int i = 0; i < 4; ++i) {
            #pragma unroll
            for (int q = 0; q < 4; ++q) {
                int row = by * BM + wm + i * 16 + lk * 4 + q;   // m89-verified C/D layout
                C[(size_t)row * GV + col] = acc[i][j][q] + bb;
            }
        }
    }
}

// ------- epilogue: argmax(+exact fixup) gather + softmax(logits) in place -------------
__global__ __launch_bounds__(256) void vq_epilogue_kernel(
    const float* __restrict__ hs,      // [T, DIMK] fp32 (original)
    const float* __restrict__ W,       // [DIMK, GV] fp32
    const float* __restrict__ bias,    // [GV]
    const float* __restrict__ gumbels, // [T*G, V]
    const float* __restrict__ cv,      // [G*V, D]
    float* __restrict__ dist,          // [T*G, V]  (holds approx logits on entry)
    float* __restrict__ out)           // [T, G*D]
{
    const int lane = threadIdx.x & 63;
    const int wid  = threadIdx.x >> 6;
    const int r = blockIdx.x * 4 + wid;          // row in [0, T*G)

    const float* lrow = dist    + (size_t)r * Vn;
    const float* grow = gumbels + (size_t)r * Vn;

    float lv[5], s[5];
    float best = -1e30f; int bidx = 0;
    float lmax = -1e30f;
    #pragma unroll
    for (int j = 0; j < 5; ++j) {
        int v = lane + j * 64;
        lv[j] = lrow[v];
        s[j] = lv[j] + grow[v];
        if (s[j] > best) { best = s[j]; bidx = v; }
        lmax = fmaxf(lmax, lv[j]);
    }

    #pragma unroll
    for (int off = 32; off > 0; off >>= 1) {
        float ob = __shfl_xor(best, off);
        int   oi = __shfl_xor(bidx, off);
        if (ob > best || (ob == best && oi < bidx)) { best = ob; bidx = oi; }
        lmax = fmaxf(lmax, __shfl_xor(lmax, off));
    }

    // ---- argmax fixup: exact fp32 recompute of all near-tie candidates ----
    const float MARGIN = 0.0625f;
    float thr = best - MARGIN;
    unsigned long long bal[5];
    int tot = 0;
    #pragma unroll
    for (int j = 0; j < 5; ++j) {
        bal[j] = __ballot(s[j] >= thr);
        tot += __popcll(bal[j]);
    }
    const int g = r & 1;
    const size_t t = (size_t)(r >> 1);
    if (tot > 1) {
        const float* hrow = hs + t * DIMK;
        float h[8];
        #pragma unroll
        for (int i = 0; i < 8; ++i) h[i] = hrow[lane * 8 + i];
        float ebest = -1e30f; int ebidx = 0x7fffffff;
        #pragma unroll
        for (int j = 0; j < 5; ++j) {
            unsigned long long m = bal[j];
            while (m) {
                int ln = __ffsll((long long)m) - 1; m &= m - 1;
                int v = ln + j * 64;
                int gvc = g * Vn + v;
                const float* wc = W + gvc;
                float p = 0.f;
                #pragma unroll
                for (int i = 0; i < 8; ++i)
                    p = fmaf(h[i], wc[(size_t)(lane * 8 + i) * GV], p);
                #pragma unroll
                for (int off = 32; off > 0; off >>= 1) p += __shfl_xor(p, off);
                float sc2 = p + bias[gvc] + grow[v];
                if (sc2 > ebest || (sc2 == ebest && v < ebidx)) { ebest = sc2; ebidx = v; }
            }
        }
        bidx = ebidx;
    }

    // ---- softmax(logits) in place ----
    float ev[5]; float ssum = 0.f;
    #pragma unroll
    for (int j = 0; j < 5; ++j) { ev[j] = expf(lv[j] - lmax); ssum += ev[j]; }
    #pragma unroll
    for (int off = 32; off > 0; off >>= 1) ssum += __shfl_xor(ssum, off);
    float inv = 1.0f / ssum;

    float* drow = dist + (size_t)r * Vn;
    #pragma unroll
    for (int j = 0; j < 5; ++j) drow[lane + j * 64] = ev[j] * inv;

    // ---- gather selected codevector (bit-exact copy) ----
    const float* cvrow = cv + ((size_t)(g * Vn + bidx)) * Dn;
    float* orow = out + t * (size_t)(Gn * Dn) + (size_t)g * Dn;
    orow[lane]      = cvrow[lane];
    orow[lane + 64] = cvrow[lane + 64];
}

extern "C" void kernel_launch(void* const* d_in, const int* in_sizes, int n_in,
                              void* d_out, int out_size, void* d_ws, size_t ws_size,
                              hipStream_t stream) {
    const float* hs  = (const float*)d_in[0];  // [8,4096,512]
    const float* W   = (const float*)d_in[1];  // [512,640]
    const float* b   = (const float*)d_in[2];  // [640]
    const float* cv  = (const float*)d_in[3];  // [640,128]
    const float* gum = (const float*)d_in[4];  // [65536,320]

    float* out  = (float*)d_out;                      // [32768, 256] fp32
    float* dist = out + (size_t)Tcnt * (Gn * Dn);     // [32768, 640] == [T*G, V]

    // A_bf16 overlays the out region (exactly 32 MB); epilogue rewrites out afterwards.
    ushort* Abf = (ushort*)d_out;
    ushort* Wt  = (ushort*)d_ws;                      // [640, 512] bf16 = 640 KB

    prep_kernel<<<8192 + 80, 256, 0, stream>>>(hs, W, Abf, Wt);

    dim3 g1((Tcnt / BM) * (GV / BN));   // 1280 blocks
    gemm_bf16_kernel<<<g1, 256, 0, stream>>>(Abf, Wt, b, dist);

    dim3 g2((Tcnt * Gn) / 4);           // 16384 blocks
    vq_epilogue_kernel<<<g2, 256, 0, stream>>>(hs, W, b, gum, cv, dist, out);
}